// Round 1
// baseline (223.477 us; speedup 1.0000x reference)
//
#include <hip/hip_runtime.h>
#include <hip/hip_bf16.h>

#define SLEN 1024
#define CDIM 256
#define TS 32
#define XROWS 34    // TS + 2 halo rows
#define XSTRIDE 36  // padded row stride (36*4B = 144B, 16B-aligned)

// ---------------------------------------------------------------------------
// Kernel 1: per-batch scan of d = round(target), build src[b][t] gather table
// ---------------------------------------------------------------------------
__global__ __launch_bounds__(1024) void scan_scatter_kernel(
    const float* __restrict__ target, int* __restrict__ src, int T)
{
    const int b = blockIdx.x;
    const int tid = threadIdx.x;

    // init gather table to -1 (zero row)
    for (int i = tid; i < T; i += 1024) src[b * T + i] = -1;

    const float tv = target[b * SLEN + tid];
    const int d = (int)rintf(tv);  // round-half-to-even, matches jnp.round

    const int lane = tid & 63;
    const int wid = tid >> 6;
    int v = d;
#pragma unroll
    for (int off = 1; off < 64; off <<= 1) {
        int n = __shfl_up(v, off);
        if (lane >= off) v += n;
    }
    __shared__ int waveSum[16];
    if (lane == 63) waveSum[wid] = v;
    __syncthreads();
    if (tid < 16) {
        int wv = waveSum[tid];
#pragma unroll
        for (int off = 1; off < 16; off <<= 1) {
            int n = __shfl_up(wv, off);
            if (tid >= off) wv += n;
        }
        waveSum[tid] = wv;
    }
    __syncthreads();
    const int fin = v + (wid > 0 ? waveSum[wid - 1] : 0);  // inclusive cumsum
    const int start = fin - d;
    for (int t = start; t < fin; ++t)
        if (t >= 0 && t < T) src[b * T + t] = tid;  // s == tid
}

// ---------------------------------------------------------------------------
// Kernel 2: expanded[b,t,:] = (src>=0) ? x[b,src,:] : 0   (one wave per row)
// ---------------------------------------------------------------------------
__global__ __launch_bounds__(256) void expand_kernel(
    const float* __restrict__ x, const int* __restrict__ src,
    float* __restrict__ out, int T)
{
    const int row = blockIdx.x * 4 + (threadIdx.x >> 6);
    const int lane = threadIdx.x & 63;
    const int nrows = 16 * T;
    if (row >= nrows) return;
    const int b = row / T;
    const int s = src[row];
    float4 val = make_float4(0.f, 0.f, 0.f, 0.f);
    if (s >= 0)
        val = *(const float4*)(x + ((size_t)(b * SLEN + s)) * CDIM + lane * 4);
    *(float4*)(out + (size_t)row * CDIM + lane * 4) = val;
}

// ---------------------------------------------------------------------------
// Kernel 3: conv1d(K=3, same) + LayerNorm(F) + ReLU
//   MODE 0: write y (B,S,F) to out
//   MODE 1: fuse final linear: reg_len[b,s] = relu(dot(y, lw) + lb)
// block = 256 threads (thread = out channel f), tile = TS positions
// ---------------------------------------------------------------------------
template <int MODE>
__global__ __launch_bounds__(256) void conv_ln_kernel(
    const float* __restrict__ in,     // (B, S, 256)
    const float* __restrict__ w,      // (256, 256, 3)
    const float* __restrict__ bias,   // (256)
    const float* __restrict__ gamma,  // (256)
    const float* __restrict__ beta,   // (256)
    float* __restrict__ out,          // MODE0: (B,S,256); MODE1: (B,S)
    const float* __restrict__ lw,     // (256)  MODE1 only
    const float* __restrict__ lb)     // (1)    MODE1 only
{
    __shared__ float xt[CDIM * XSTRIDE];  // transposed x tile [c][r], 36 KB
    __shared__ float ot[TS * CDIM];       // LN reduction buffer, 32 KB
    __shared__ float s_mean[TS], s_rs[TS];

    const int f = threadIdx.x;
    const int s0 = blockIdx.x * TS;
    const int b = blockIdx.y;
    const float* xin = in + (size_t)b * SLEN * CDIM;

    // stage x rows s0-1 .. s0+TS transposed into LDS (zero-pad out of range)
    for (int i = f; i < XROWS * CDIM; i += 256) {
        const int r = i >> 8;
        const int c = i & 255;
        const int s = s0 - 1 + r;
        float v = (s >= 0 && s < SLEN) ? xin[(size_t)s * CDIM + c] : 0.f;
        xt[c * XSTRIDE + r] = v;
    }
    __syncthreads();

    float acc[TS];
#pragma unroll
    for (int t = 0; t < TS; ++t) acc[t] = 0.f;

    const float4* wrow = (const float4*)(w + (size_t)f * (CDIM * 3));
    for (int c4 = 0; c4 < CDIM / 4; ++c4) {
        const float4 W0 = wrow[c4 * 3 + 0];
        const float4 W1 = wrow[c4 * 3 + 1];
        const float4 W2 = wrow[c4 * 3 + 2];
        const float wk[12] = {W0.x, W0.y, W0.z, W0.w,
                              W1.x, W1.y, W1.z, W1.w,
                              W2.x, W2.y, W2.z, W2.w};
#pragma unroll
        for (int j = 0; j < 4; ++j) {
            const int c = c4 * 4 + j;
            const float4* xr4 = (const float4*)(xt + c * XSTRIDE);
            float xr[36];
#pragma unroll
            for (int qi = 0; qi < 9; ++qi) {
                const float4 q = xr4[qi];  // wave-uniform broadcast read
                xr[4 * qi + 0] = q.x;
                xr[4 * qi + 1] = q.y;
                xr[4 * qi + 2] = q.z;
                xr[4 * qi + 3] = q.w;
            }
            const float w0 = wk[j * 3 + 0];
            const float w1 = wk[j * 3 + 1];
            const float w2 = wk[j * 3 + 2];
#pragma unroll
            for (int t = 0; t < TS; ++t)
                acc[t] = fmaf(xr[t], w0,
                         fmaf(xr[t + 1], w1,
                         fmaf(xr[t + 2], w2, acc[t])));
        }
    }

    const float bv = bias[f];
#pragma unroll
    for (int t = 0; t < TS; ++t) acc[t] += bv;

    // ---- LayerNorm over f (256 channels) for each of TS positions ----
#pragma unroll
    for (int t = 0; t < TS; ++t) ot[t * CDIM + f] = acc[t];
    __syncthreads();

    const int g8 = f & 7;   // 8 threads per position
    const int tl = f >> 3;  // position handled by this group
    float sum = 0.f, sq = 0.f;
#pragma unroll
    for (int j2 = 0; j2 < 32; ++j2) {
        const float v = ot[tl * CDIM + g8 + j2 * 8];
        sum += v;
        sq = fmaf(v, v, sq);
    }
#pragma unroll
    for (int off = 1; off < 8; off <<= 1) {
        sum += __shfl_xor(sum, off);
        sq += __shfl_xor(sq, off);
    }
    if (g8 == 0) {
        const float mean = sum * (1.f / 256.f);
        const float var = sq * (1.f / 256.f) - mean * mean;
        s_mean[tl] = mean;
        s_rs[tl] = rsqrtf(var + 1e-5f);
    }
    __syncthreads();

    const float ga = gamma[f];
    const float be = beta[f];
    if (MODE == 0) {
        float* o = out + ((size_t)b * SLEN + s0) * CDIM + f;
#pragma unroll
        for (int t = 0; t < TS; ++t) {
            const float v = (acc[t] - s_mean[t]) * s_rs[t] * ga + be;
            o[(size_t)t * CDIM] = fmaxf(v, 0.f);
        }
    } else {
        const float lwf = lw[f];
#pragma unroll
        for (int t = 0; t < TS; ++t) {
            const float v = (acc[t] - s_mean[t]) * s_rs[t] * ga + be;
            ot[t * CDIM + f] = fmaxf(v, 0.f) * lwf;
        }
        __syncthreads();
        float s2 = 0.f;
#pragma unroll
        for (int j2 = 0; j2 < 32; ++j2) s2 += ot[tl * CDIM + g8 + j2 * 8];
#pragma unroll
        for (int off = 1; off < 8; off <<= 1) s2 += __shfl_xor(s2, off);
        if (g8 == 0)
            out[b * SLEN + s0 + tl] = fmaxf(s2 + lb[0], 0.f);
    }
}

// ---------------------------------------------------------------------------
extern "C" void kernel_launch(void* const* d_in, const int* in_sizes, int n_in,
                              void* d_out, int out_size, void* d_ws, size_t ws_size,
                              hipStream_t stream)
{
    const float* x       = (const float*)d_in[0];
    const float* target  = (const float*)d_in[1];
    const float* conv1_w = (const float*)d_in[2];
    const float* conv1_b = (const float*)d_in[3];
    const float* conv2_w = (const float*)d_in[4];
    const float* conv2_b = (const float*)d_in[5];
    const float* ln1_g   = (const float*)d_in[6];
    const float* ln1_b   = (const float*)d_in[7];
    const float* ln2_g   = (const float*)d_in[8];
    const float* ln2_b   = (const float*)d_in[9];
    const float* lin_w   = (const float*)d_in[10];
    const float* lin_b   = (const float*)d_in[11];

    const int B = 16, S = 1024, C = 256;
    const int T = (out_size - B * S) / (B * C);  // max_len, from harness out_size

    float* expanded = (float*)d_out;                       // (B, T, C)
    float* reg_len  = (float*)d_out + (size_t)B * T * C;   // (B, S)
    float* y1  = (float*)d_ws;                             // (B, S, C) intermediate
    int*   src = (int*)((float*)d_ws + (size_t)B * S * C); // (B, T) gather table

    scan_scatter_kernel<<<B, 1024, 0, stream>>>(target, src, T);

    conv_ln_kernel<0><<<dim3(S / TS, B), 256, 0, stream>>>(
        x, conv1_w, conv1_b, ln1_g, ln1_b, y1, nullptr, nullptr);

    const int nrows = B * T;
    expand_kernel<<<(nrows + 3) / 4, 256, 0, stream>>>(x, src, expanded, T);

    conv_ln_kernel<1><<<dim3(S / TS, B), 256, 0, stream>>>(
        y1, conv2_w, conv2_b, ln2_g, ln2_b, reg_len, lin_w, lin_b);
}

// Round 2
// 62.907 us; speedup vs baseline: 3.5525x; 3.5525x over previous
//
#include <hip/hip_runtime.h>
#include <hip/hip_bf16.h>

using frag_ab = __attribute__((ext_vector_type(8))) short;  // 8 bf16
using frag_cd = __attribute__((ext_vector_type(4))) float;  // 4 fp32

#define SLEN 1024
#define CDIM 256
#define KTOT 768  // 3 * 256

static __device__ __forceinline__ short f2bf(float f) {
    __hip_bfloat16 h = __float2bfloat16(f);
    return *reinterpret_cast<short*>(&h);
}

// ---------------------------------------------------------------------------
// Kernel 1: per-batch scan of d = round(target), build src[b][t] gather table
// ---------------------------------------------------------------------------
__global__ __launch_bounds__(1024) void scan_scatter_kernel(
    const float* __restrict__ target, int* __restrict__ src, int T)
{
    const int b = blockIdx.x;
    const int tid = threadIdx.x;

    for (int i = tid; i < T; i += 1024) src[b * T + i] = -1;

    const float tv = target[b * SLEN + tid];
    const int d = (int)rintf(tv);

    const int lane = tid & 63;
    const int wid = tid >> 6;
    int v = d;
#pragma unroll
    for (int off = 1; off < 64; off <<= 1) {
        int n = __shfl_up(v, off);
        if (lane >= off) v += n;
    }
    __shared__ int waveSum[16];
    if (lane == 63) waveSum[wid] = v;
    __syncthreads();
    if (tid < 16) {
        int wv = waveSum[tid];
#pragma unroll
        for (int off = 1; off < 16; off <<= 1) {
            int n = __shfl_up(wv, off);
            if (tid >= off) wv += n;
        }
        waveSum[tid] = wv;
    }
    __syncthreads();
    const int fin = v + (wid > 0 ? waveSum[wid - 1] : 0);
    const int start = fin - d;
    for (int t = start; t < fin; ++t)
        if (t >= 0 && t < T) src[b * T + t] = tid;
}

// ---------------------------------------------------------------------------
// Kernel 2: expanded[b,t,:] = (src>=0) ? x[b,src,:] : 0   (one wave per row)
// ---------------------------------------------------------------------------
__global__ __launch_bounds__(256) void expand_kernel(
    const float* __restrict__ x, const int* __restrict__ src,
    float* __restrict__ out, int T)
{
    const int row = blockIdx.x * 4 + (threadIdx.x >> 6);
    const int lane = threadIdx.x & 63;
    const int nrows = 16 * T;
    if (row >= nrows) return;
    const int b = row / T;
    const int s = src[row];
    float4 val = make_float4(0.f, 0.f, 0.f, 0.f);
    if (s >= 0)
        val = *(const float4*)(x + ((size_t)(b * SLEN + s)) * CDIM + lane * 4);
    *(float4*)(out + (size_t)row * CDIM + lane * 4) = val;
}

// ---------------------------------------------------------------------------
// Kernel 3: repack conv weight (F, C, 3) fp32 -> Bt[f][k3*256 + c] bf16
// ---------------------------------------------------------------------------
__global__ __launch_bounds__(256) void repack_w(
    const float* __restrict__ w, __hip_bfloat16* __restrict__ bt)
{
    const int f = blockIdx.y;
    const int K = blockIdx.x * 256 + threadIdx.x;  // 0..767
    const int k3 = K >> 8;
    const int c = K & 255;
    bt[f * KTOT + K] = __float2bfloat16(w[f * KTOT + c * 3 + k3]);
}

// ---------------------------------------------------------------------------
// Kernel 4: MFMA conv1d(K=3,same) + bias + LayerNorm + ReLU
//   MODE 0: input fp32 x, output bf16 y1 (B,S,C)
//   MODE 1: input bf16 y1, fuse linear: reg_len = relu(dot(y, lw) + lb)
// Block: 512 threads = 8 waves; tile 64 rows x 256 ch; wave = 64 rows x 32 ch.
// A staged in LDS (bf16, XOR-swizzled), B-fragments direct from L2.
// ---------------------------------------------------------------------------
template <int MODE>
__global__ __launch_bounds__(512) void conv_mfma(
    const void* __restrict__ in_,
    const __hip_bfloat16* __restrict__ bt,
    const float* __restrict__ bias,
    const float* __restrict__ gamma,
    const float* __restrict__ beta,
    void* __restrict__ out_,
    const float* __restrict__ lw,
    const float* __restrict__ lb)
{
    __shared__ __align__(16) unsigned char ldsA[66 * 512];  // 33 KB, reused for y-tile
    __shared__ float red[64][8][2];
    __shared__ float stats[64][2];

    const int tid = threadIdx.x;
    const int b = blockIdx.y;
    const int s0 = blockIdx.x * 64;

    // ---- stage rows s0-1 .. s0+64 into LDS as swizzled bf16 [66][256] ----
    if (MODE == 0) {
        const float* xin = (const float*)in_ + (size_t)b * SLEN * CDIM;
        for (int ii = tid; ii < 66 * 32; ii += 512) {
            const int r = ii >> 5, cc = ii & 31;
            const int s = s0 + r - 1;
            frag_ab v = {0, 0, 0, 0, 0, 0, 0, 0};
            if (s >= 0 && s < SLEN) {
                const float4* p = (const float4*)(xin + (size_t)s * CDIM + cc * 8);
                const float4 q0 = p[0], q1 = p[1];
                v[0] = f2bf(q0.x); v[1] = f2bf(q0.y); v[2] = f2bf(q0.z); v[3] = f2bf(q0.w);
                v[4] = f2bf(q1.x); v[5] = f2bf(q1.y); v[6] = f2bf(q1.z); v[7] = f2bf(q1.w);
            }
            *(frag_ab*)(ldsA + r * 512 + ((cc * 16) ^ ((r & 7) << 4))) = v;
        }
    } else {
        const __hip_bfloat16* yin = (const __hip_bfloat16*)in_ + (size_t)b * SLEN * CDIM;
        for (int ii = tid; ii < 66 * 32; ii += 512) {
            const int r = ii >> 5, cc = ii & 31;
            const int s = s0 + r - 1;
            frag_ab v = {0, 0, 0, 0, 0, 0, 0, 0};
            if (s >= 0 && s < SLEN)
                v = *(const frag_ab*)(yin + (size_t)s * CDIM + cc * 8);
            *(frag_ab*)(ldsA + r * 512 + ((cc * 16) ^ ((r & 7) << 4))) = v;
        }
    }
    __syncthreads();

    const int lane = tid & 63;
    const int wid = tid >> 6;   // 0..7 -> 32-col slice
    const int l15 = lane & 15;
    const int lk = lane >> 4;   // k-group 0..3
    const int fbase = wid * 32;

    frag_cd acc[4][2];
#pragma unroll
    for (int mf = 0; mf < 4; ++mf) {
        acc[mf][0] = {0.f, 0.f, 0.f, 0.f};
        acc[mf][1] = {0.f, 0.f, 0.f, 0.f};
    }

    const __hip_bfloat16* bt0 = bt + (size_t)(fbase + l15) * KTOT + lk * 8;
    const __hip_bfloat16* bt1 = bt0 + 16 * KTOT;

#pragma unroll
    for (int kk = 0; kk < 24; ++kk) {
        const int k3 = kk >> 3;
        const int colbyte = (kk & 7) * 64 + lk * 16;
        const frag_ab bb0 = *(const frag_ab*)(bt0 + kk * 32);
        const frag_ab bb1 = *(const frag_ab*)(bt1 + kk * 32);
        frag_ab a[4];
#pragma unroll
        for (int mf = 0; mf < 4; ++mf) {
            const int r = mf * 16 + l15 + k3;
            a[mf] = *(const frag_ab*)(ldsA + r * 512 + (colbyte ^ ((r & 7) << 4)));
        }
#pragma unroll
        for (int mf = 0; mf < 4; ++mf) {
            acc[mf][0] = __builtin_amdgcn_mfma_f32_16x16x32_bf16(a[mf], bb0, acc[mf][0], 0, 0, 0);
            acc[mf][1] = __builtin_amdgcn_mfma_f32_16x16x32_bf16(a[mf], bb1, acc[mf][1], 0, 0, 0);
        }
    }

    // ---- bias + per-row sum/sumsq reduction ----
    const float bias0 = bias[fbase + l15];
    const float bias1 = bias[fbase + 16 + l15];
#pragma unroll
    for (int mf = 0; mf < 4; ++mf) {
#pragma unroll
        for (int j = 0; j < 4; ++j) {
            acc[mf][0][j] += bias0;
            acc[mf][1][j] += bias1;
            float p = acc[mf][0][j] + acc[mf][1][j];
            float q = acc[mf][0][j] * acc[mf][0][j] + acc[mf][1][j] * acc[mf][1][j];
#pragma unroll
            for (int m = 1; m < 16; m <<= 1) {
                p += __shfl_xor(p, m);
                q += __shfl_xor(q, m);
            }
            if (l15 == 0) {
                const int row = mf * 16 + lk * 4 + j;
                red[row][wid][0] = p;
                red[row][wid][1] = q;
            }
        }
    }
    __syncthreads();
    if (tid < 64) {
        float s = 0.f, q = 0.f;
#pragma unroll
        for (int wv = 0; wv < 8; ++wv) { s += red[tid][wv][0]; q += red[tid][wv][1]; }
        const float mean = s * (1.f / 256.f);
        const float var = q * (1.f / 256.f) - mean * mean;
        stats[tid][0] = mean;
        stats[tid][1] = rsqrtf(var + 1e-5f);
    }
    __syncthreads();

    const float g0 = gamma[fbase + l15], g1 = gamma[fbase + 16 + l15];
    const float be0 = beta[fbase + l15], be1 = beta[fbase + 16 + l15];

    if (MODE == 0) {
        // normalized bf16 -> LDS y-tile (linear [64][256]) -> coalesced store
#pragma unroll
        for (int mf = 0; mf < 4; ++mf) {
#pragma unroll
            for (int j = 0; j < 4; ++j) {
                const int row = mf * 16 + lk * 4 + j;
                const float mean = stats[row][0], rs = stats[row][1];
                const float v0 = fmaxf((acc[mf][0][j] - mean) * rs * g0 + be0, 0.f);
                const float v1 = fmaxf((acc[mf][1][j] - mean) * rs * g1 + be1, 0.f);
                *(short*)(ldsA + row * 512 + (fbase + l15) * 2) = f2bf(v0);
                *(short*)(ldsA + row * 512 + (fbase + 16 + l15) * 2) = f2bf(v1);
            }
        }
        __syncthreads();
        __hip_bfloat16* yout = (__hip_bfloat16*)out_ + ((size_t)b * SLEN + s0) * CDIM;
        for (int ii = tid; ii < 64 * 32; ii += 512) {
            const int r = ii >> 5, cc = ii & 31;
            *(frag_ab*)(yout + (size_t)r * CDIM + cc * 8) =
                *(const frag_ab*)(ldsA + r * 512 + cc * 16);
        }
    } else {
        const float lw0 = lw[fbase + l15], lw1 = lw[fbase + 16 + l15];
#pragma unroll
        for (int mf = 0; mf < 4; ++mf) {
#pragma unroll
            for (int j = 0; j < 4; ++j) {
                const int row = mf * 16 + lk * 4 + j;
                const float mean = stats[row][0], rs = stats[row][1];
                const float v0 = fmaxf((acc[mf][0][j] - mean) * rs * g0 + be0, 0.f);
                const float v1 = fmaxf((acc[mf][1][j] - mean) * rs * g1 + be1, 0.f);
                float p = v0 * lw0 + v1 * lw1;
#pragma unroll
                for (int m = 1; m < 16; m <<= 1) p += __shfl_xor(p, m);
                if (l15 == 0) red[row][wid][0] = p;
            }
        }
        __syncthreads();
        if (tid < 64) {
            float s = 0.f;
#pragma unroll
            for (int wv = 0; wv < 8; ++wv) s += red[tid][wv][0];
            ((float*)out_)[b * SLEN + s0 + tid] = fmaxf(s + lb[0], 0.f);
        }
    }
}

// ---------------------------------------------------------------------------
extern "C" void kernel_launch(void* const* d_in, const int* in_sizes, int n_in,
                              void* d_out, int out_size, void* d_ws, size_t ws_size,
                              hipStream_t stream)
{
    const float* x       = (const float*)d_in[0];
    const float* target  = (const float*)d_in[1];
    const float* conv1_w = (const float*)d_in[2];
    const float* conv1_b = (const float*)d_in[3];
    const float* conv2_w = (const float*)d_in[4];
    const float* conv2_b = (const float*)d_in[5];
    const float* ln1_g   = (const float*)d_in[6];
    const float* ln1_b   = (const float*)d_in[7];
    const float* ln2_g   = (const float*)d_in[8];
    const float* ln2_b   = (const float*)d_in[9];
    const float* lin_w   = (const float*)d_in[10];
    const float* lin_b   = (const float*)d_in[11];

    const int B = 16, S = 1024, C = 256;
    const int T = (out_size - B * S) / (B * C);

    float* expanded = (float*)d_out;                      // (B, T, C)
    float* reg_len  = (float*)d_out + (size_t)B * T * C;  // (B, S)

    unsigned char* ws = (unsigned char*)d_ws;
    __hip_bfloat16* y1  = (__hip_bfloat16*)ws;                        // 8 MB
    __hip_bfloat16* bt1 = (__hip_bfloat16*)(ws + 8388608);            // 384 KB
    __hip_bfloat16* bt2 = (__hip_bfloat16*)(ws + 8388608 + 393216);   // 384 KB
    int* src = (int*)(ws + 8388608 + 2 * 393216);                     // (B, T)

    scan_scatter_kernel<<<B, 1024, 0, stream>>>(target, src, T);
    repack_w<<<dim3(3, 256), 256, 0, stream>>>(conv1_w, bt1);
    repack_w<<<dim3(3, 256), 256, 0, stream>>>(conv2_w, bt2);

    conv_mfma<0><<<dim3(16, 16), 512, 0, stream>>>(
        x, bt1, conv1_b, ln1_g, ln1_b, y1, nullptr, nullptr);

    expand_kernel<<<(B * T + 3) / 4, 256, 0, stream>>>(x, src, expanded, T);

    conv_mfma<1><<<dim3(16, 16), 512, 0, stream>>>(
        y1, bt2, conv2_b, ln2_g, ln2_b, reg_len, lin_w, lin_b);
}

// Round 3
// 57.075 us; speedup vs baseline: 3.9155x; 1.1022x over previous
//
#include <hip/hip_runtime.h>
#include <hip/hip_bf16.h>

using frag_ab = __attribute__((ext_vector_type(8))) short;  // 8 bf16
using frag_cd = __attribute__((ext_vector_type(4))) float;  // 4 fp32

#define SLEN 1024
#define CDIM 256
#define KTOT 768  // 3 * 256

static __device__ __forceinline__ short f2bf(float f) {
    __hip_bfloat16 h = __float2bfloat16(f);
    return *reinterpret_cast<short*>(&h);
}

// ---------------------------------------------------------------------------
// Kernel 1: per-batch scan of d = round(target), build src[b][t] gather table
// ---------------------------------------------------------------------------
__global__ __launch_bounds__(1024) void scan_scatter_kernel(
    const float* __restrict__ target, int* __restrict__ src, int T)
{
    const int b = blockIdx.x;
    const int tid = threadIdx.x;

    for (int i = tid; i < T; i += 1024) src[b * T + i] = -1;

    const float tv = target[b * SLEN + tid];
    const int d = (int)rintf(tv);

    const int lane = tid & 63;
    const int wid = tid >> 6;
    int v = d;
#pragma unroll
    for (int off = 1; off < 64; off <<= 1) {
        int n = __shfl_up(v, off);
        if (lane >= off) v += n;
    }
    __shared__ int waveSum[16];
    if (lane == 63) waveSum[wid] = v;
    __syncthreads();
    if (tid < 16) {
        int wv = waveSum[tid];
#pragma unroll
        for (int off = 1; off < 16; off <<= 1) {
            int n = __shfl_up(wv, off);
            if (tid >= off) wv += n;
        }
        waveSum[tid] = wv;
    }
    __syncthreads();
    const int fin = v + (wid > 0 ? waveSum[wid - 1] : 0);
    const int start = fin - d;
    for (int t = start; t < fin; ++t)
        if (t >= 0 && t < T) src[b * T + t] = tid;
}

// ---------------------------------------------------------------------------
// Kernel 2: expanded[b,t,:] = (src>=0) ? x[b,src,:] : 0   (one wave per row)
// ---------------------------------------------------------------------------
__global__ __launch_bounds__(256) void expand_kernel(
    const float* __restrict__ x, const int* __restrict__ src,
    float* __restrict__ out, int T)
{
    const int row = blockIdx.x * 4 + (threadIdx.x >> 6);
    const int lane = threadIdx.x & 63;
    const int nrows = 16 * T;
    if (row >= nrows) return;
    const int b = row / T;
    const int s = src[row];
    float4 val = make_float4(0.f, 0.f, 0.f, 0.f);
    if (s >= 0)
        val = *(const float4*)(x + ((size_t)(b * SLEN + s)) * CDIM + lane * 4);
    *(float4*)(out + (size_t)row * CDIM + lane * 4) = val;
}

// ---------------------------------------------------------------------------
// Kernel 3: repack BOTH conv weights (F, C, 3) fp32 -> Bt[f][k3*256 + c] bf16
// ---------------------------------------------------------------------------
__global__ __launch_bounds__(256) void repack_w2(
    const float* __restrict__ w1, __hip_bfloat16* __restrict__ bt1,
    const float* __restrict__ w2, __hip_bfloat16* __restrict__ bt2)
{
    const int f = blockIdx.y;
    const int which = blockIdx.x / 3;
    const int K = (blockIdx.x % 3) * 256 + threadIdx.x;  // 0..767
    const int k3 = K >> 8;
    const int c = K & 255;
    const float* w = which ? w2 : w1;
    __hip_bfloat16* bt = which ? bt2 : bt1;
    bt[f * KTOT + K] = __float2bfloat16(w[f * KTOT + c * 3 + k3]);
}

// ---------------------------------------------------------------------------
// Kernel 4: FUSED conv1+LN1+ReLU+conv2+LN2+ReLU+linear -> reg_len
// Block: 512 thr = 8 waves; tile 64 output rows; conv1 computes 66 rows
// (halo recompute via 5th M-fragment); y-tile lives in LDS (bf16 swizzled).
// ---------------------------------------------------------------------------
__global__ __launch_bounds__(512) void fused_conv(
    const float* __restrict__ x,
    const __hip_bfloat16* __restrict__ bt1,
    const __hip_bfloat16* __restrict__ bt2,
    const float* __restrict__ cb1, const float* __restrict__ g1, const float* __restrict__ be1,
    const float* __restrict__ cb2, const float* __restrict__ g2, const float* __restrict__ be2,
    const float* __restrict__ lw, const float* __restrict__ lb,
    float* __restrict__ reg_len)
{
    __shared__ __align__(16) unsigned char xt[82 * 512];  // x tile, rows s0-2..s0+65 (+garbage pad)
    __shared__ __align__(16) unsigned char yt[66 * 512];  // y tile, rows s0-1..s0+64
    __shared__ float red[66][8][2];
    __shared__ float stats[66][2];

    const int tid = threadIdx.x;
    const int b = blockIdx.y;
    const int s0 = blockIdx.x * 64;

    // ---- stage x rows s0-2 .. s0+65 as swizzled bf16 ----
    const float* xin = x + (size_t)b * SLEN * CDIM;
    for (int ii = tid; ii < 68 * 32; ii += 512) {
        const int r = ii >> 5, cc = ii & 31;
        const int s = s0 - 2 + r;
        frag_ab v = {0, 0, 0, 0, 0, 0, 0, 0};
        if (s >= 0 && s < SLEN) {
            const float4* p = (const float4*)(xin + (size_t)s * CDIM + cc * 8);
            const float4 q0 = p[0], q1 = p[1];
            v[0] = f2bf(q0.x); v[1] = f2bf(q0.y); v[2] = f2bf(q0.z); v[3] = f2bf(q0.w);
            v[4] = f2bf(q1.x); v[5] = f2bf(q1.y); v[6] = f2bf(q1.z); v[7] = f2bf(q1.w);
        }
        *(frag_ab*)(xt + r * 512 + ((cc * 16) ^ ((r & 7) << 4))) = v;
    }
    __syncthreads();

    const int lane = tid & 63;
    const int wid = tid >> 6;
    const int l15 = lane & 15;
    const int lk = lane >> 4;
    const int fbase = wid * 32;

    // ================= conv1: y rows s0-1 .. s0+64 (66 rows, 5 frags) ======
    frag_cd acc1[5][2];
#pragma unroll
    for (int mf = 0; mf < 5; ++mf) {
        acc1[mf][0] = {0.f, 0.f, 0.f, 0.f};
        acc1[mf][1] = {0.f, 0.f, 0.f, 0.f};
    }
    {
        const __hip_bfloat16* p0 = bt1 + (size_t)(fbase + l15) * KTOT + lk * 8;
        const __hip_bfloat16* p1 = p0 + 16 * KTOT;
#pragma unroll
        for (int kk = 0; kk < 24; ++kk) {
            const int k3 = kk >> 3;
            const int colbyte = (kk & 7) * 64 + lk * 16;
            const frag_ab bb0 = *(const frag_ab*)(p0 + kk * 32);
            const frag_ab bb1 = *(const frag_ab*)(p1 + kk * 32);
            frag_ab a[5];
#pragma unroll
            for (int mf = 0; mf < 5; ++mf) {
                const int r = mf * 16 + l15 + k3;  // frag covers y rows 16mf-1+p
                a[mf] = *(const frag_ab*)(xt + r * 512 + (colbyte ^ ((r & 7) << 4)));
            }
#pragma unroll
            for (int mf = 0; mf < 5; ++mf) {
                acc1[mf][0] = __builtin_amdgcn_mfma_f32_16x16x32_bf16(a[mf], bb0, acc1[mf][0], 0, 0, 0);
                acc1[mf][1] = __builtin_amdgcn_mfma_f32_16x16x32_bf16(a[mf], bb1, acc1[mf][1], 0, 0, 0);
            }
        }
    }

    // ---- bias1 + LN1 row-stat reduction (rows yr = 0..65 <-> s0-1..s0+64) --
    {
        const float bias0 = cb1[fbase + l15];
        const float bias1 = cb1[fbase + 16 + l15];
#pragma unroll
        for (int mf = 0; mf < 5; ++mf) {
#pragma unroll
            for (int j = 0; j < 4; ++j) {
                acc1[mf][0][j] += bias0;
                acc1[mf][1][j] += bias1;
                float p = acc1[mf][0][j] + acc1[mf][1][j];
                float q = acc1[mf][0][j] * acc1[mf][0][j] + acc1[mf][1][j] * acc1[mf][1][j];
#pragma unroll
                for (int m = 1; m < 16; m <<= 1) {
                    p += __shfl_xor(p, m);
                    q += __shfl_xor(q, m);
                }
                const bool valid = (mf < 4) || (lk == 0 && j < 2);
                if (l15 == 0 && valid) {
                    const int yr = mf * 16 + lk * 4 + j;  // 0..65
                    red[yr][wid][0] = p;
                    red[yr][wid][1] = q;
                }
            }
        }
    }
    __syncthreads();
    if (tid < 66) {
        float s = 0.f, q = 0.f;
#pragma unroll
        for (int wv = 0; wv < 8; ++wv) { s += red[tid][wv][0]; q += red[tid][wv][1]; }
        const float mean = s * (1.f / 256.f);
        const float var = q * (1.f / 256.f) - mean * mean;
        stats[tid][0] = mean;
        stats[tid][1] = rsqrtf(var + 1e-5f);
    }
    __syncthreads();

    // ---- LN1+ReLU -> y tile (bf16, swizzled) ----
    {
        const float ga0 = g1[fbase + l15], ga1 = g1[fbase + 16 + l15];
        const float bb0 = be1[fbase + l15], bb1 = be1[fbase + 16 + l15];
        const int c0b = (fbase + l15) * 2;
        const int c1b = (fbase + 16 + l15) * 2;
#pragma unroll
        for (int mf = 0; mf < 5; ++mf) {
#pragma unroll
            for (int j = 0; j < 4; ++j) {
                const bool valid = (mf < 4) || (lk == 0 && j < 2);
                if (valid) {
                    const int yr = mf * 16 + lk * 4 + j;
                    const float mean = stats[yr][0], rs = stats[yr][1];
                    const float v0 = fmaxf((acc1[mf][0][j] - mean) * rs * ga0 + bb0, 0.f);
                    const float v1 = fmaxf((acc1[mf][1][j] - mean) * rs * ga1 + bb1, 0.f);
                    const int sw = (yr & 7) << 4;
                    *(short*)(yt + yr * 512 + (c0b ^ sw)) = f2bf(v0);
                    *(short*)(yt + yr * 512 + (c1b ^ sw)) = f2bf(v1);
                }
            }
        }
    }
    __syncthreads();
    // conv2 'same' padding: zero y rows outside [0, SLEN)
    if (blockIdx.x == 0 && tid < 32) {
        frag_ab z = {0, 0, 0, 0, 0, 0, 0, 0};
        *(frag_ab*)(yt + (tid * 16)) = z;  // row 0, (0&7)<<4 = 0
    }
    if (blockIdx.x == 15 && tid >= 64 && tid < 96) {
        frag_ab z = {0, 0, 0, 0, 0, 0, 0, 0};
        const int cc = tid - 64;
        *(frag_ab*)(yt + 65 * 512 + ((cc * 16) ^ ((65 & 7) << 4))) = z;
    }
    __syncthreads();

    // ================= conv2 on y tile (64 output rows) =====================
    frag_cd acc2[4][2];
#pragma unroll
    for (int mf = 0; mf < 4; ++mf) {
        acc2[mf][0] = {0.f, 0.f, 0.f, 0.f};
        acc2[mf][1] = {0.f, 0.f, 0.f, 0.f};
    }
    {
        const __hip_bfloat16* p0 = bt2 + (size_t)(fbase + l15) * KTOT + lk * 8;
        const __hip_bfloat16* p1 = p0 + 16 * KTOT;
#pragma unroll
        for (int kk = 0; kk < 24; ++kk) {
            const int k3 = kk >> 3;
            const int colbyte = (kk & 7) * 64 + lk * 16;
            const frag_ab bb0 = *(const frag_ab*)(p0 + kk * 32);
            const frag_ab bb1 = *(const frag_ab*)(p1 + kk * 32);
            frag_ab a[4];
#pragma unroll
            for (int mf = 0; mf < 4; ++mf) {
                const int r = mf * 16 + l15 + k3;  // yt row, max 65
                a[mf] = *(const frag_ab*)(yt + r * 512 + (colbyte ^ ((r & 7) << 4)));
            }
#pragma unroll
            for (int mf = 0; mf < 4; ++mf) {
                acc2[mf][0] = __builtin_amdgcn_mfma_f32_16x16x32_bf16(a[mf], bb0, acc2[mf][0], 0, 0, 0);
                acc2[mf][1] = __builtin_amdgcn_mfma_f32_16x16x32_bf16(a[mf], bb1, acc2[mf][1], 0, 0, 0);
            }
        }
    }

    // ---- bias2 + LN2 stats ----
    {
        const float bias0 = cb2[fbase + l15];
        const float bias1 = cb2[fbase + 16 + l15];
#pragma unroll
        for (int mf = 0; mf < 4; ++mf) {
#pragma unroll
            for (int j = 0; j < 4; ++j) {
                acc2[mf][0][j] += bias0;
                acc2[mf][1][j] += bias1;
                float p = acc2[mf][0][j] + acc2[mf][1][j];
                float q = acc2[mf][0][j] * acc2[mf][0][j] + acc2[mf][1][j] * acc2[mf][1][j];
#pragma unroll
                for (int m = 1; m < 16; m <<= 1) {
                    p += __shfl_xor(p, m);
                    q += __shfl_xor(q, m);
                }
                if (l15 == 0) {
                    const int row = mf * 16 + lk * 4 + j;
                    red[row][wid][0] = p;
                    red[row][wid][1] = q;
                }
            }
        }
    }
    __syncthreads();
    if (tid < 64) {
        float s = 0.f, q = 0.f;
#pragma unroll
        for (int wv = 0; wv < 8; ++wv) { s += red[tid][wv][0]; q += red[tid][wv][1]; }
        const float mean = s * (1.f / 256.f);
        const float var = q * (1.f / 256.f) - mean * mean;
        stats[tid][0] = mean;
        stats[tid][1] = rsqrtf(var + 1e-5f);
    }
    __syncthreads();

    // ---- LN2 + ReLU + linear dot -> reg_len ----
    {
        const float ga0 = g2[fbase + l15], ga1 = g2[fbase + 16 + l15];
        const float bb0 = be2[fbase + l15], bb1 = be2[fbase + 16 + l15];
        const float lw0 = lw[fbase + l15], lw1 = lw[fbase + 16 + l15];
#pragma unroll
        for (int mf = 0; mf < 4; ++mf) {
#pragma unroll
            for (int j = 0; j < 4; ++j) {
                const int row = mf * 16 + lk * 4 + j;
                const float mean = stats[row][0], rs = stats[row][1];
                const float v0 = fmaxf((acc2[mf][0][j] - mean) * rs * ga0 + bb0, 0.f);
                const float v1 = fmaxf((acc2[mf][1][j] - mean) * rs * ga1 + bb1, 0.f);
                float p = v0 * lw0 + v1 * lw1;
#pragma unroll
                for (int m = 1; m < 16; m <<= 1) p += __shfl_xor(p, m);
                if (l15 == 0) red[row][wid][0] = p;
            }
        }
    }
    __syncthreads();
    if (tid < 64) {
        float s = 0.f;
#pragma unroll
        for (int wv = 0; wv < 8; ++wv) s += red[tid][wv][0];
        reg_len[b * SLEN + s0 + tid] = fmaxf(s + lb[0], 0.f);
    }
}

// ---------------------------------------------------------------------------
extern "C" void kernel_launch(void* const* d_in, const int* in_sizes, int n_in,
                              void* d_out, int out_size, void* d_ws, size_t ws_size,
                              hipStream_t stream)
{
    const float* x       = (const float*)d_in[0];
    const float* target  = (const float*)d_in[1];
    const float* conv1_w = (const float*)d_in[2];
    const float* conv1_b = (const float*)d_in[3];
    const float* conv2_w = (const float*)d_in[4];
    const float* conv2_b = (const float*)d_in[5];
    const float* ln1_g   = (const float*)d_in[6];
    const float* ln1_b   = (const float*)d_in[7];
    const float* ln2_g   = (const float*)d_in[8];
    const float* ln2_b   = (const float*)d_in[9];
    const float* lin_w   = (const float*)d_in[10];
    const float* lin_b   = (const float*)d_in[11];

    const int B = 16, S = 1024, C = 256;
    const int T = (out_size - B * S) / (B * C);

    float* expanded = (float*)d_out;                      // (B, T, C)
    float* reg_len  = (float*)d_out + (size_t)B * T * C;  // (B, S)

    unsigned char* ws = (unsigned char*)d_ws;
    __hip_bfloat16* bt1 = (__hip_bfloat16*)ws;              // 384 KB
    __hip_bfloat16* bt2 = (__hip_bfloat16*)(ws + 393216);   // 384 KB
    int* src = (int*)(ws + 2 * 393216);                     // (B, T)

    scan_scatter_kernel<<<B, 1024, 0, stream>>>(target, src, T);
    repack_w2<<<dim3(6, 256), 256, 0, stream>>>(conv1_w, bt1, conv2_w, bt2);

    fused_conv<<<dim3(16, 16), 512, 0, stream>>>(
        x, bt1, bt2, conv1_b, ln1_g, ln1_b, conv2_b, ln2_g, ln2_b,
        lin_w, lin_b, reg_len);

    expand_kernel<<<(B * T + 3) / 4, 256, 0, stream>>>(x, src, expanded, T);
}

// Round 4
// 56.748 us; speedup vs baseline: 3.9380x; 1.0058x over previous
//
#include <hip/hip_runtime.h>
#include <hip/hip_bf16.h>

using frag_ab = __attribute__((ext_vector_type(8))) short;  // 8 bf16
using frag_cd = __attribute__((ext_vector_type(4))) float;  // 4 fp32

#define SLEN 1024
#define CDIM 256
#define KTOT 768  // 3 * 256
#define PD 8      // B-fragment prefetch depth

static __device__ __forceinline__ short f2bf(float f) {
    __hip_bfloat16 h = __float2bfloat16(f);
    return *reinterpret_cast<short*>(&h);
}

// ---------------------------------------------------------------------------
// Kernel 1: per-batch scan of d = round(target), build src[b][t] gather table
// ---------------------------------------------------------------------------
__global__ __launch_bounds__(1024) void scan_scatter_kernel(
    const float* __restrict__ target, int* __restrict__ src, int T)
{
    const int b = blockIdx.x;
    const int tid = threadIdx.x;

    for (int i = tid; i < T; i += 1024) src[b * T + i] = -1;

    const float tv = target[b * SLEN + tid];
    const int d = (int)rintf(tv);

    const int lane = tid & 63;
    const int wid = tid >> 6;
    int v = d;
#pragma unroll
    for (int off = 1; off < 64; off <<= 1) {
        int n = __shfl_up(v, off);
        if (lane >= off) v += n;
    }
    __shared__ int waveSum[16];
    if (lane == 63) waveSum[wid] = v;
    __syncthreads();
    if (tid < 16) {
        int wv = waveSum[tid];
#pragma unroll
        for (int off = 1; off < 16; off <<= 1) {
            int n = __shfl_up(wv, off);
            if (tid >= off) wv += n;
        }
        waveSum[tid] = wv;
    }
    __syncthreads();
    const int fin = v + (wid > 0 ? waveSum[wid - 1] : 0);
    const int start = fin - d;
    for (int t = start; t < fin; ++t)
        if (t >= 0 && t < T) src[b * T + t] = tid;
}

// ---------------------------------------------------------------------------
// Kernel 2: expanded[b,t,:] = (src>=0) ? x[b,src,:] : 0   (one wave per row)
// ---------------------------------------------------------------------------
__global__ __launch_bounds__(256) void expand_kernel(
    const float* __restrict__ x, const int* __restrict__ src,
    float* __restrict__ out, int T)
{
    const int row = blockIdx.x * 4 + (threadIdx.x >> 6);
    const int lane = threadIdx.x & 63;
    const int nrows = 16 * T;
    if (row >= nrows) return;
    const int b = row / T;
    const int s = src[row];
    float4 val = make_float4(0.f, 0.f, 0.f, 0.f);
    if (s >= 0)
        val = *(const float4*)(x + ((size_t)(b * SLEN + s)) * CDIM + lane * 4);
    *(float4*)(out + (size_t)row * CDIM + lane * 4) = val;
}

// ---------------------------------------------------------------------------
// Kernel 3: repack BOTH conv weights (F, C, 3) fp32 -> Bt[f][k3*256 + c] bf16
// ---------------------------------------------------------------------------
__global__ __launch_bounds__(256) void repack_w2(
    const float* __restrict__ w1, __hip_bfloat16* __restrict__ bt1,
    const float* __restrict__ w2, __hip_bfloat16* __restrict__ bt2)
{
    const int f = blockIdx.y;
    const int which = blockIdx.x / 3;
    const int K = (blockIdx.x % 3) * 256 + threadIdx.x;  // 0..767
    const int k3 = K >> 8;
    const int c = K & 255;
    const float* w = which ? w2 : w1;
    __hip_bfloat16* bt = which ? bt2 : bt1;
    bt[f * KTOT + K] = __float2bfloat16(w[f * KTOT + c * 3 + k3]);
}

// ---------------------------------------------------------------------------
// Kernel 4: FUSED conv1+LN1+ReLU+conv2+LN2+ReLU+linear -> reg_len
// Block: 512 thr = 8 waves; tile 64 output rows; conv1 computes 66 rows
// (halo recompute via 5th M-fragment); y-tile lives in LDS (bf16 swizzled).
// B-fragments prefetched 8 deep from L2 (launch_bounds(512,2): VGPR cap 256,
// occupancy unchanged at 1 block/CU since grid == 256).
// ---------------------------------------------------------------------------
__global__ __launch_bounds__(512, 2) void fused_conv(
    const float* __restrict__ x,
    const __hip_bfloat16* __restrict__ bt1,
    const __hip_bfloat16* __restrict__ bt2,
    const float* __restrict__ cb1, const float* __restrict__ g1, const float* __restrict__ be1,
    const float* __restrict__ cb2, const float* __restrict__ g2, const float* __restrict__ be2,
    const float* __restrict__ lw, const float* __restrict__ lb,
    float* __restrict__ reg_len)
{
    __shared__ __align__(16) unsigned char xt[68 * 512];  // x tile rows s0-2..s0+65 (reads clamped)
    __shared__ __align__(16) unsigned char yt[66 * 512];  // y tile rows s0-1..s0+64
    __shared__ float red[66][8][2];
    __shared__ float stats[66][2];

    const int tid = threadIdx.x;
    const int b = blockIdx.y;
    const int s0 = blockIdx.x * 64;

    const int lane = tid & 63;
    const int wid = tid >> 6;
    const int l15 = lane & 15;
    const int lk = lane >> 4;
    const int fbase = wid * 32;

    // ---- issue conv1 B prefetch FIRST (overlaps with x staging below) ----
    const __hip_bfloat16* p10 = bt1 + (size_t)(fbase + l15) * KTOT + lk * 8;
    const __hip_bfloat16* p11 = p10 + 16 * KTOT;
    frag_ab pb0[PD], pb1[PD];
#pragma unroll
    for (int i = 0; i < PD; ++i) {
        pb0[i] = *(const frag_ab*)(p10 + i * 32);
        pb1[i] = *(const frag_ab*)(p11 + i * 32);
    }

    // ---- stage x rows s0-2 .. s0+65 as swizzled bf16 ----
    const float* xin = x + (size_t)b * SLEN * CDIM;
    for (int ii = tid; ii < 68 * 32; ii += 512) {
        const int r = ii >> 5, cc = ii & 31;
        const int s = s0 - 2 + r;
        frag_ab v = {0, 0, 0, 0, 0, 0, 0, 0};
        if (s >= 0 && s < SLEN) {
            const float4* p = (const float4*)(xin + (size_t)s * CDIM + cc * 8);
            const float4 q0 = p[0], q1 = p[1];
            v[0] = f2bf(q0.x); v[1] = f2bf(q0.y); v[2] = f2bf(q0.z); v[3] = f2bf(q0.w);
            v[4] = f2bf(q1.x); v[5] = f2bf(q1.y); v[6] = f2bf(q1.z); v[7] = f2bf(q1.w);
        }
        *(frag_ab*)(xt + r * 512 + ((cc * 16) ^ ((r & 7) << 4))) = v;
    }
    __syncthreads();

    // ================= conv1: y rows s0-1 .. s0+64 (66 rows, 5 frags) ======
    frag_cd acc1[5][2];
#pragma unroll
    for (int mf = 0; mf < 5; ++mf) {
        acc1[mf][0] = {0.f, 0.f, 0.f, 0.f};
        acc1[mf][1] = {0.f, 0.f, 0.f, 0.f};
    }
#pragma unroll
    for (int kk = 0; kk < 24; ++kk) {
        const frag_ab bb0 = pb0[kk % PD];
        const frag_ab bb1 = pb1[kk % PD];
        if (kk + PD < 24) {
            pb0[kk % PD] = *(const frag_ab*)(p10 + (kk + PD) * 32);
            pb1[kk % PD] = *(const frag_ab*)(p11 + (kk + PD) * 32);
        }
        const int k3 = kk >> 3;
        const int colbyte = (kk & 7) * 64 + lk * 16;
        frag_ab a[5];
#pragma unroll
        for (int mf = 0; mf < 5; ++mf) {
            int r = mf * 16 + l15 + k3;
            if (mf == 4) r = (r > 67) ? 67 : r;  // clamp: rows >67 feed discarded outputs
            a[mf] = *(const frag_ab*)(xt + r * 512 + (colbyte ^ ((r & 7) << 4)));
        }
#pragma unroll
        for (int mf = 0; mf < 5; ++mf) {
            acc1[mf][0] = __builtin_amdgcn_mfma_f32_16x16x32_bf16(a[mf], bb0, acc1[mf][0], 0, 0, 0);
            acc1[mf][1] = __builtin_amdgcn_mfma_f32_16x16x32_bf16(a[mf], bb1, acc1[mf][1], 0, 0, 0);
        }
    }

    // ---- issue conv2 B prefetch now; latency hides under LN1 epilogue ----
    const __hip_bfloat16* p20 = bt2 + (size_t)(fbase + l15) * KTOT + lk * 8;
    const __hip_bfloat16* p21 = p20 + 16 * KTOT;
    frag_ab qb0[PD], qb1[PD];
#pragma unroll
    for (int i = 0; i < PD; ++i) {
        qb0[i] = *(const frag_ab*)(p20 + i * 32);
        qb1[i] = *(const frag_ab*)(p21 + i * 32);
    }

    // ---- bias1 + LN1 row-stat reduction (rows yr = 0..65) ----
    {
        const float bias0 = cb1[fbase + l15];
        const float bias1 = cb1[fbase + 16 + l15];
#pragma unroll
        for (int mf = 0; mf < 5; ++mf) {
#pragma unroll
            for (int j = 0; j < 4; ++j) {
                acc1[mf][0][j] += bias0;
                acc1[mf][1][j] += bias1;
                float p = acc1[mf][0][j] + acc1[mf][1][j];
                float q = acc1[mf][0][j] * acc1[mf][0][j] + acc1[mf][1][j] * acc1[mf][1][j];
#pragma unroll
                for (int m = 1; m < 16; m <<= 1) {
                    p += __shfl_xor(p, m);
                    q += __shfl_xor(q, m);
                }
                const bool valid = (mf < 4) || (lk == 0 && j < 2);
                if (l15 == 0 && valid) {
                    const int yr = mf * 16 + lk * 4 + j;  // 0..65
                    red[yr][wid][0] = p;
                    red[yr][wid][1] = q;
                }
            }
        }
    }
    __syncthreads();
    if (tid < 66) {
        float s = 0.f, q = 0.f;
#pragma unroll
        for (int wv = 0; wv < 8; ++wv) { s += red[tid][wv][0]; q += red[tid][wv][1]; }
        const float mean = s * (1.f / 256.f);
        const float var = q * (1.f / 256.f) - mean * mean;
        stats[tid][0] = mean;
        stats[tid][1] = rsqrtf(var + 1e-5f);
    }
    __syncthreads();

    // ---- LN1+ReLU -> y tile (bf16, swizzled) ----
    {
        const float ga0 = g1[fbase + l15], ga1 = g1[fbase + 16 + l15];
        const float bb0 = be1[fbase + l15], bb1 = be1[fbase + 16 + l15];
        const int c0b = (fbase + l15) * 2;
        const int c1b = (fbase + 16 + l15) * 2;
#pragma unroll
        for (int mf = 0; mf < 5; ++mf) {
#pragma unroll
            for (int j = 0; j < 4; ++j) {
                const bool valid = (mf < 4) || (lk == 0 && j < 2);
                if (valid) {
                    const int yr = mf * 16 + lk * 4 + j;
                    const float mean = stats[yr][0], rs = stats[yr][1];
                    const float v0 = fmaxf((acc1[mf][0][j] - mean) * rs * ga0 + bb0, 0.f);
                    const float v1 = fmaxf((acc1[mf][1][j] - mean) * rs * ga1 + bb1, 0.f);
                    const int sw = (yr & 7) << 4;
                    *(short*)(yt + yr * 512 + (c0b ^ sw)) = f2bf(v0);
                    *(short*)(yt + yr * 512 + (c1b ^ sw)) = f2bf(v1);
                }
            }
        }
    }
    __syncthreads();
    // conv2 'same' padding: zero y rows outside [0, SLEN)
    if (blockIdx.x == 0 && tid < 32) {
        frag_ab z = {0, 0, 0, 0, 0, 0, 0, 0};
        *(frag_ab*)(yt + (tid * 16)) = z;  // row 0, (0&7)<<4 = 0
    }
    if (blockIdx.x == 15 && tid >= 64 && tid < 96) {
        frag_ab z = {0, 0, 0, 0, 0, 0, 0, 0};
        const int cc = tid - 64;
        *(frag_ab*)(yt + 65 * 512 + ((cc * 16) ^ ((65 & 7) << 4))) = z;
    }
    __syncthreads();

    // ================= conv2 on y tile (64 output rows) =====================
    frag_cd acc2[4][2];
#pragma unroll
    for (int mf = 0; mf < 4; ++mf) {
        acc2[mf][0] = {0.f, 0.f, 0.f, 0.f};
        acc2[mf][1] = {0.f, 0.f, 0.f, 0.f};
    }
#pragma unroll
    for (int kk = 0; kk < 24; ++kk) {
        const frag_ab bb0 = qb0[kk % PD];
        const frag_ab bb1 = qb1[kk % PD];
        if (kk + PD < 24) {
            qb0[kk % PD] = *(const frag_ab*)(p20 + (kk + PD) * 32);
            qb1[kk % PD] = *(const frag_ab*)(p21 + (kk + PD) * 32);
        }
        const int k3 = kk >> 3;
        const int colbyte = (kk & 7) * 64 + lk * 16;
        frag_ab a[4];
#pragma unroll
        for (int mf = 0; mf < 4; ++mf) {
            const int r = mf * 16 + l15 + k3;  // yt row, max 65
            a[mf] = *(const frag_ab*)(yt + r * 512 + (colbyte ^ ((r & 7) << 4)));
        }
#pragma unroll
        for (int mf = 0; mf < 4; ++mf) {
            acc2[mf][0] = __builtin_amdgcn_mfma_f32_16x16x32_bf16(a[mf], bb0, acc2[mf][0], 0, 0, 0);
            acc2[mf][1] = __builtin_amdgcn_mfma_f32_16x16x32_bf16(a[mf], bb1, acc2[mf][1], 0, 0, 0);
        }
    }

    // ---- bias2 + LN2 stats ----
    {
        const float bias0 = cb2[fbase + l15];
        const float bias1 = cb2[fbase + 16 + l15];
#pragma unroll
        for (int mf = 0; mf < 4; ++mf) {
#pragma unroll
            for (int j = 0; j < 4; ++j) {
                acc2[mf][0][j] += bias0;
                acc2[mf][1][j] += bias1;
                float p = acc2[mf][0][j] + acc2[mf][1][j];
                float q = acc2[mf][0][j] * acc2[mf][0][j] + acc2[mf][1][j] * acc2[mf][1][j];
#pragma unroll
                for (int m = 1; m < 16; m <<= 1) {
                    p += __shfl_xor(p, m);
                    q += __shfl_xor(q, m);
                }
                if (l15 == 0) {
                    const int row = mf * 16 + lk * 4 + j;
                    red[row][wid][0] = p;
                    red[row][wid][1] = q;
                }
            }
        }
    }
    __syncthreads();
    if (tid < 64) {
        float s = 0.f, q = 0.f;
#pragma unroll
        for (int wv = 0; wv < 8; ++wv) { s += red[tid][wv][0]; q += red[tid][wv][1]; }
        const float mean = s * (1.f / 256.f);
        const float var = q * (1.f / 256.f) - mean * mean;
        stats[tid][0] = mean;
        stats[tid][1] = rsqrtf(var + 1e-5f);
    }
    __syncthreads();

    // ---- LN2 + ReLU + linear dot -> reg_len ----
    {
        const float ga0 = g2[fbase + l15], ga1 = g2[fbase + 16 + l15];
        const float bb0 = be2[fbase + l15], bb1 = be2[fbase + 16 + l15];
        const float lw0 = lw[fbase + l15], lw1 = lw[fbase + 16 + l15];
#pragma unroll
        for (int mf = 0; mf < 4; ++mf) {
#pragma unroll
            for (int j = 0; j < 4; ++j) {
                const int row = mf * 16 + lk * 4 + j;
                const float mean = stats[row][0], rs = stats[row][1];
                const float v0 = fmaxf((acc2[mf][0][j] - mean) * rs * ga0 + bb0, 0.f);
                const float v1 = fmaxf((acc2[mf][1][j] - mean) * rs * ga1 + bb1, 0.f);
                float p = v0 * lw0 + v1 * lw1;
#pragma unroll
                for (int m = 1; m < 16; m <<= 1) p += __shfl_xor(p, m);
                if (l15 == 0) red[row][wid][0] = p;
            }
        }
    }
    __syncthreads();
    if (tid < 64) {
        float s = 0.f;
#pragma unroll
        for (int wv = 0; wv < 8; ++wv) s += red[tid][wv][0];
        reg_len[b * SLEN + s0 + tid] = fmaxf(s + lb[0], 0.f);
    }
}

// ---------------------------------------------------------------------------
extern "C" void kernel_launch(void* const* d_in, const int* in_sizes, int n_in,
                              void* d_out, int out_size, void* d_ws, size_t ws_size,
                              hipStream_t stream)
{
    const float* x       = (const float*)d_in[0];
    const float* target  = (const float*)d_in[1];
    const float* conv1_w = (const float*)d_in[2];
    const float* conv1_b = (const float*)d_in[3];
    const float* conv2_w = (const float*)d_in[4];
    const float* conv2_b = (const float*)d_in[5];
    const float* ln1_g   = (const float*)d_in[6];
    const float* ln1_b   = (const float*)d_in[7];
    const float* ln2_g   = (const float*)d_in[8];
    const float* ln2_b   = (const float*)d_in[9];
    const float* lin_w   = (const float*)d_in[10];
    const float* lin_b   = (const float*)d_in[11];

    const int B = 16, S = 1024, C = 256;
    const int T = (out_size - B * S) / (B * C);

    float* expanded = (float*)d_out;                      // (B, T, C)
    float* reg_len  = (float*)d_out + (size_t)B * T * C;  // (B, S)

    unsigned char* ws = (unsigned char*)d_ws;
    __hip_bfloat16* bt1 = (__hip_bfloat16*)ws;              // 384 KB
    __hip_bfloat16* bt2 = (__hip_bfloat16*)(ws + 393216);   // 384 KB
    int* src = (int*)(ws + 2 * 393216);                     // (B, T)

    scan_scatter_kernel<<<B, 1024, 0, stream>>>(target, src, T);
    repack_w2<<<dim3(6, 256), 256, 0, stream>>>(conv1_w, bt1, conv2_w, bt2);

    fused_conv<<<dim3(16, 16), 512, 0, stream>>>(
        x, bt1, bt2, conv1_b, ln1_g, ln1_b, conv2_b, ln2_g, ln2_b,
        lin_w, lin_b, reg_len);

    expand_kernel<<<(B * T + 3) / 4, 256, 0, stream>>>(x, src, expanded, T);
}